// Round 1
// baseline (5511.940 us; speedup 1.0000x reference)
//
#include <hip/hip_runtime.h>
#include <cmath>

#define B_ 8
#define T_ 64
#define N_ 256
#define F_ 64
#define C_ 128
#define O_ 32
#define H_ 1024
#define NC_ 16

__device__ __forceinline__ float sigf(float x){ return 1.f/(1.f+expf(-x)); }

// ---------------- K0: attr_eff[g][j][i] ----------------
__global__ __launch_bounds__(256) void attr_kernel(const float* __restrict__ V, float* __restrict__ attr){
  __shared__ float sv[32][33];
  __shared__ float selfv[32];
  int g = blockIdx.x, tid = threadIdx.x;
  for (int idx = tid; idx < 1024; idx += 256){
    int j = idx >> 5, i = idx & 31;
    sv[j][i] = sigf(V[(size_t)(g*32 + j)*256 + g*32 + i]);
  }
  __syncthreads();
  if (tid < 32){
    float s = 0.f;
    for (int j = 0; j < 32; ++j) if (j != tid) s += sv[j][tid];
    selfv[tid] = s * (1.f/31.f);
  }
  __syncthreads();
  for (int idx = tid; idx < 1024; idx += 256){
    int j = idx >> 5, i = idx & 31;
    attr[g*1024 + idx] = (j == i) ? selfv[i] : sv[j][i];
  }
}

// ---------------- K1: projections (+ fused fc for b>0) ----------------
// block = (b,t,g). b==0: store gl0, gr0. b>0: y = (gl+gat_bias)@Wfc^T + bfc -> xl
__global__ __launch_bounds__(256) void proj_kernel(
    const float* __restrict__ X, const float* __restrict__ Wl, const float* __restrict__ bl,
    const float* __restrict__ Wr, const float* __restrict__ br,
    const float* __restrict__ gbias, const float* __restrict__ Wfc, const float* __restrict__ bfc,
    float* __restrict__ gl0, float* __restrict__ gr0, float* __restrict__ xl){
  __shared__ float smem[2080 + 8320 + 8320];   // Xs[32][65] | Wls[128][65] | union(Wrs[128][65] , gls[32][129]+Wfcs[32][129])
  float* Xs  = smem;
  float* Wls = smem + 2080;
  float* R2  = smem + 2080 + 8320;
  int tid = threadIdx.x, blk = blockIdx.x;
  int g = blk & 7, t = (blk >> 3) & 63, b = blk >> 9;

  const float* Xp = X + ((size_t)(b*T_ + t)*N_ + g*32)*F_;
  for (int idx = tid; idx < 2048; idx += 256){
    int n = idx >> 6, k = idx & 63;
    Xs[n*65 + k] = Xp[idx];
  }
  for (int idx = tid; idx < 8192; idx += 256){
    int c = idx >> 6, k = idx & 63;
    Wls[c*65 + k] = Wl[idx];
  }
  if (b == 0){
    for (int idx = tid; idx < 8192; idx += 256){
      int c = idx >> 6, k = idx & 63;
      R2[c*65 + k] = Wr[idx];
    }
  } else {
    for (int idx = tid; idx < 4096; idx += 256){
      int o = idx >> 7, c = idx & 127;
      R2[4128 + o*129 + c] = Wfc[idx];
    }
  }
  __syncthreads();

  int c = tid & 127, nb = (tid >> 7) * 16;
  if (b == 0){
    float accL[16], accR[16];
    float blv = bl[c], brv = br[c];
    #pragma unroll
    for (int p = 0; p < 16; ++p){ accL[p] = blv; accR[p] = brv; }
    for (int k = 0; k < 64; ++k){
      float wl = Wls[c*65 + k], wr = R2[c*65 + k];
      #pragma unroll
      for (int p = 0; p < 16; ++p){
        float xv = Xs[(nb+p)*65 + k];
        accL[p] = fmaf(wl, xv, accL[p]);
        accR[p] = fmaf(wr, xv, accR[p]);
      }
    }
    size_t base = ((size_t)t*N_ + g*32)*C_;
    #pragma unroll
    for (int p = 0; p < 16; ++p){
      gl0[base + (size_t)(nb+p)*C_ + c] = accL[p];
      gr0[base + (size_t)(nb+p)*C_ + c] = accR[p];
    }
  } else {
    float accL[16];
    float blv = bl[c];
    #pragma unroll
    for (int p = 0; p < 16; ++p) accL[p] = blv;
    for (int k = 0; k < 64; ++k){
      float wl = Wls[c*65 + k];
      #pragma unroll
      for (int p = 0; p < 16; ++p)
        accL[p] = fmaf(wl, Xs[(nb+p)*65 + k], accL[p]);
    }
    float* gls = R2;           // [32][129]
    float gbv = gbias[c];
    #pragma unroll
    for (int p = 0; p < 16; ++p) gls[(nb+p)*129 + c] = accL[p] + gbv;
    __syncthreads();
    float* Wfcs = R2 + 4128;   // [32][129]
    int o = tid & 31, n2b = tid >> 5;
    float bfv = bfc[o];
    for (int p = 0; p < 4; ++p){
      int n2 = n2b + 8*p;
      float acc = bfv;
      for (int cc = 0; cc < 128; ++cc)
        acc = fmaf(gls[n2*129 + cc], Wfcs[o*129 + cc], acc);
      xl[((size_t)(b*T_ + t)*N_ + g*32 + n2)*O_ + o] = acc;
    }
  }
}

// ---------------- K2: attention for b==0 (+ fused fc) ----------------
// block = (t,g)
__global__ __launch_bounds__(256) void attn_kernel(
    const float* __restrict__ gl0, const float* __restrict__ gr0,
    const float* __restrict__ attr, const float* __restrict__ we, const float* __restrict__ att,
    const float* __restrict__ gbias, const float* __restrict__ Wfc, const float* __restrict__ bfc,
    float* __restrict__ xl){
  __shared__ float gls[32*129], grs[32*129], os_[32*129], Wfcs[32*129];
  __shared__ float ae[32*33], Ss[32*33];
  __shared__ float wes[128], atts[128];
  int tid = threadIdx.x, blk = blockIdx.x;
  int g = blk & 7, t = blk >> 3;

  const float* glp = gl0 + ((size_t)t*N_ + g*32)*C_;
  const float* grp = gr0 + ((size_t)t*N_ + g*32)*C_;
  for (int idx = tid; idx < 4096; idx += 256){
    int n = idx >> 7, c = idx & 127;
    gls[n*129 + c]  = glp[idx];
    grs[n*129 + c]  = grp[idx];
    Wfcs[n*129 + c] = Wfc[idx];
  }
  for (int idx = tid; idx < 1024; idx += 256) ae[(idx>>5)*33 + (idx&31)] = attr[g*1024 + idx];
  if (tid < 128){ wes[tid] = we[tid]; atts[tid] = att[tid]; }
  __syncthreads();

  // S[i][j] = sum_c lrelu(gl[j,c] + gr[i,c] + attr_eff[j,i]*we[c]) * att[c]
  int i = tid >> 3, jb = (tid & 7) * 4;
  float a0 = ae[(jb+0)*33 + i], a1 = ae[(jb+1)*33 + i], a2 = ae[(jb+2)*33 + i], a3 = ae[(jb+3)*33 + i];
  float s0 = 0.f, s1 = 0.f, s2 = 0.f, s3 = 0.f;
  for (int cc = 0; cc < 128; ++cc){
    float grv = grs[i*129 + cc];
    float wv = wes[cc], av = atts[cc];
    float p0 = gls[(jb+0)*129 + cc] + grv + a0*wv;
    float p1 = gls[(jb+1)*129 + cc] + grv + a1*wv;
    float p2 = gls[(jb+2)*129 + cc] + grv + a2*wv;
    float p3 = gls[(jb+3)*129 + cc] + grv + a3*wv;
    p0 = p0 > 0.f ? p0 : 0.2f*p0;
    p1 = p1 > 0.f ? p1 : 0.2f*p1;
    p2 = p2 > 0.f ? p2 : 0.2f*p2;
    p3 = p3 > 0.f ? p3 : 0.2f*p3;
    s0 = fmaf(p0, av, s0); s1 = fmaf(p1, av, s1);
    s2 = fmaf(p2, av, s2); s3 = fmaf(p3, av, s3);
  }
  Ss[i*33 + jb + 0] = s0; Ss[i*33 + jb + 1] = s1;
  Ss[i*33 + jb + 2] = s2; Ss[i*33 + jb + 3] = s3;
  __syncthreads();

  if (tid < 32){
    float mx = -1e30f;
    for (int j = 0; j < 32; ++j) mx = fmaxf(mx, Ss[tid*33 + j]);
    float sum = 0.f;
    for (int j = 0; j < 32; ++j) sum += expf(Ss[tid*33 + j] - mx);
    float inv = 1.f / sum;
    for (int j = 0; j < 32; ++j) Ss[tid*33 + j] = expf(Ss[tid*33 + j] - mx) * inv;
  }
  __syncthreads();

  // out0[i][c] = sum_j alpha[i][j]*gl[j][c]  (+gat_bias)
  int c2 = tid & 127, ibase = (tid >> 7) * 16;
  float gbv = gbias[c2];
  for (int p = 0; p < 16; ++p){
    int ii = ibase + p;
    float acc = 0.f;
    #pragma unroll
    for (int j = 0; j < 32; ++j) acc = fmaf(Ss[ii*33 + j], gls[j*129 + c2], acc);
    os_[ii*129 + c2] = acc + gbv;
  }
  __syncthreads();

  int o = tid & 31, n2b = tid >> 5;
  float bfv = bfc[o];
  for (int p = 0; p < 4; ++p){
    int n2 = n2b + 8*p;
    float acc = bfv;
    for (int cc = 0; cc < 128; ++cc)
      acc = fmaf(os_[n2*129 + cc], Wfcs[o*129 + cc], acc);
    xl[((size_t)t*N_ + g*32 + n2)*O_ + o] = acc;   // b == 0
  }
}

// ---------------- K4/K6: Y[m][n] = sum_k A[m][k]*W[n][k] + b1[n] + b2[n] ----------------
__global__ __launch_bounds__(256) void gemm_nt(
    const float* __restrict__ A, const float* __restrict__ W,
    const float* __restrict__ b1, const float* __restrict__ b2,
    float* __restrict__ Y, int M, int N, int K){
  __shared__ __align__(16) float As[32*68];
  __shared__ __align__(16) float Ws[32*68];
  int tid = threadIdx.x;
  int m0 = blockIdx.x * 64, n0 = blockIdx.y * 64;
  int tx = tid & 15, ty = tid >> 4;
  float acc[4][4] = {{0.f}};
  for (int kc = 0; kc < K; kc += 32){
    for (int idx = tid; idx < 2048; idx += 256){
      int r = idx >> 5, k = idx & 31;
      As[k*68 + r] = A[(size_t)(m0 + r)*K + kc + k];
      Ws[k*68 + r] = W[(size_t)(n0 + r)*K + kc + k];
    }
    __syncthreads();
    #pragma unroll 4
    for (int k = 0; k < 32; ++k){
      float4 av = *(const float4*)&As[k*68 + ty*4];
      float4 wv = *(const float4*)&Ws[k*68 + tx*4];
      float am[4] = {av.x, av.y, av.z, av.w};
      float wn[4] = {wv.x, wv.y, wv.z, wv.w};
      #pragma unroll
      for (int mm = 0; mm < 4; ++mm)
        #pragma unroll
        for (int nn = 0; nn < 4; ++nn)
          acc[mm][nn] = fmaf(am[mm], wn[nn], acc[mm][nn]);
    }
    __syncthreads();
  }
  #pragma unroll
  for (int mm = 0; mm < 4; ++mm){
    int m = m0 + ty*4 + mm;
    #pragma unroll
    for (int nn = 0; nn < 4; ++nn){
      int n = n0 + tx*4 + nn;
      Y[(size_t)m*N + n] = acc[mm][nn] + b1[n] + b2[n];
    }
  }
}

// ---------------- K5: one LSTM timestep ----------------
// grid 128 blocks: block owns 8 h-dims (x4 gates x 8 batches). gates = i,f,g,o rows q*H+dim.
__global__ __launch_bounds__(256) void lstm_step(
    const float* __restrict__ Whh, const float* __restrict__ xg,
    const float* __restrict__ hprev_seq, float* __restrict__ h_seq,
    float* __restrict__ c_buf, int t){
  __shared__ float hs[8*1024];
  int tid = threadIdx.x;
  if (t == 0){
    for (int idx = tid; idx < 8192; idx += 256) hs[idx] = 0.f;
  } else {
    for (int idx = tid; idx < 8192; idx += 256){
      int b = idx >> 10, k = idx & 1023;
      hs[idx] = hprev_seq[((size_t)b*T_ + (t-1))*H_ + k];
    }
  }
  __syncthreads();

  int b = tid >> 5, rl = tid & 31;
  int q = rl >> 3, d = rl & 7;
  int dim = blockIdx.x * 8 + d;
  int row = q*H_ + dim;
  const float4* wp = (const float4*)(Whh + (size_t)row*H_);
  const float4* hp = (const float4*)(hs + b*1024);
  float sv = 0.f;
  for (int k = 0; k < 256; ++k){
    float4 w = wp[k], h = hp[k];
    sv = fmaf(w.x, h.x, sv); sv = fmaf(w.y, h.y, sv);
    sv = fmaf(w.z, h.z, sv); sv = fmaf(w.w, h.w, sv);
  }
  sv += xg[((size_t)b*T_ + t)*4096 + row];

  int lane = tid & 63;
  float vf = __shfl(sv, (lane + 8)  & 63, 64);
  float vg = __shfl(sv, (lane + 16) & 63, 64);
  float vo = __shfl(sv, (lane + 24) & 63, 64);
  if (q == 0){
    float i_ = sigf(sv);
    float f_ = sigf(vf);
    float g_ = tanhf(vg);
    float o_ = sigf(vo);
    float cp = (t == 0) ? 0.f : c_buf[b*H_ + dim];
    float cn = fmaf(f_, cp, i_*g_);
    float hn = o_ * tanhf(cn);
    c_buf[b*H_ + dim] = cn;
    h_seq[((size_t)b*T_ + t)*H_ + dim] = hn;
  }
}

// ---------------- K8: final head ----------------
__global__ __launch_bounds__(128) void final_kernel(
    const float* __restrict__ h2_seq, const float* __restrict__ Wout,
    const float* __restrict__ bout, float* __restrict__ out){
  int tid = threadIdx.x;
  int b = tid >> 4, nc = tid & 15;
  const float* hp = h2_seq + ((size_t)b*T_ + (T_ - 1))*H_;
  const float* wp = Wout + nc*H_;
  float acc = bout[nc];
  for (int k = 0; k < 1024; ++k) acc = fmaf(hp[k], wp[k], acc);
  out[tid] = acc;
}

extern "C" void kernel_launch(void* const* d_in, const int* in_sizes, int n_in,
                              void* d_out, int out_size, void* d_ws, size_t ws_size,
                              hipStream_t stream){
  const float* X    = (const float*)d_in[0];
  const float* V    = (const float*)d_in[1];
  const float* Wl   = (const float*)d_in[2];
  const float* bl   = (const float*)d_in[3];
  const float* Wr   = (const float*)d_in[4];
  const float* br   = (const float*)d_in[5];
  const float* att  = (const float*)d_in[6];
  const float* we   = (const float*)d_in[7];
  const float* gb   = (const float*)d_in[8];
  const float* Wfc  = (const float*)d_in[9];
  const float* bfc  = (const float*)d_in[10];
  const float* Wih0 = (const float*)d_in[11];
  const float* Whh0 = (const float*)d_in[12];
  const float* bih0 = (const float*)d_in[13];
  const float* bhh0 = (const float*)d_in[14];
  const float* Wih1 = (const float*)d_in[15];
  const float* Whh1 = (const float*)d_in[16];
  const float* bih1 = (const float*)d_in[17];
  const float* bhh1 = (const float*)d_in[18];
  const float* Wout = (const float*)d_in[19];
  const float* bout = (const float*)d_in[20];

  float* ws   = (float*)d_ws;
  float* attr = ws;                   // 8192
  float* gl0  = attr + 8192;          // 2097152
  float* gr0  = gl0 + 2097152;        // 2097152
  float* xl   = gr0 + 2097152;        // 4194304 (B,T,8192)
  float* xg0  = xl + 4194304;         // 2097152 (B,T,4096)
  float* xg1  = xg0 + 2097152;        // 2097152
  float* hseq = xg1 + 2097152;        // 524288  (B,T,1024)
  float* h2sq = hseq + 524288;        // 524288
  float* c0   = h2sq + 524288;        // 8192
  float* c1   = c0 + 8192;            // 8192
  (void)in_sizes; (void)n_in; (void)out_size; (void)ws_size;

  attr_kernel<<<8, 256, 0, stream>>>(V, attr);
  proj_kernel<<<4096, 256, 0, stream>>>(X, Wl, bl, Wr, br, gb, Wfc, bfc, gl0, gr0, xl);
  attn_kernel<<<512, 256, 0, stream>>>(gl0, gr0, attr, we, att, gb, Wfc, bfc, xl);

  gemm_nt<<<dim3(8, 64), 256, 0, stream>>>(xl, Wih0, bih0, bhh0, xg0, 512, 4096, 8192);
  for (int t = 0; t < 64; ++t)
    lstm_step<<<128, 256, 0, stream>>>(Whh0, xg0, hseq, hseq, c0, t);

  gemm_nt<<<dim3(8, 64), 256, 0, stream>>>(hseq, Wih1, bih1, bhh1, xg1, 512, 4096, 1024);
  for (int t = 0; t < 64; ++t)
    lstm_step<<<128, 256, 0, stream>>>(Whh1, xg1, h2sq, h2sq, c1, t);

  final_kernel<<<1, 128, 0, stream>>>(h2sq, Wout, bout, (float*)d_out);
}

// Round 2
// 1393.375 us; speedup vs baseline: 3.9558x; 3.9558x over previous
//
#include <hip/hip_runtime.h>
#include <cmath>

#define B_ 8
#define T_ 64
#define N_ 256
#define F_ 64
#define C_ 128
#define O_ 32
#define H_ 1024
#define NC_ 16

typedef __attribute__((ext_vector_type(8))) short bf16x8;
typedef __attribute__((ext_vector_type(4))) float f32x4;

__device__ __forceinline__ float sigf(float x){ return 1.f/(1.f+expf(-x)); }

__device__ __forceinline__ unsigned short f2bf(float f){
  unsigned int u = __float_as_uint(f);
  u += 0x7fff + ((u >> 16) & 1);          // round-to-nearest-even
  return (unsigned short)(u >> 16);
}

// ---------------- K0: attr_eff[g][j][i] ----------------
__global__ __launch_bounds__(256) void attr_kernel(const float* __restrict__ V, float* __restrict__ attr){
  __shared__ float sv[32][33];
  __shared__ float selfv[32];
  int g = blockIdx.x, tid = threadIdx.x;
  for (int idx = tid; idx < 1024; idx += 256){
    int j = idx >> 5, i = idx & 31;
    sv[j][i] = sigf(V[(size_t)(g*32 + j)*256 + g*32 + i]);
  }
  __syncthreads();
  if (tid < 32){
    float s = 0.f;
    for (int j = 0; j < 32; ++j) if (j != tid) s += sv[j][tid];
    selfv[tid] = s * (1.f/31.f);
  }
  __syncthreads();
  for (int idx = tid; idx < 1024; idx += 256){
    int j = idx >> 5, i = idx & 31;
    attr[g*1024 + idx] = (j == i) ? selfv[i] : sv[j][i];
  }
}

// ---------------- K1: projections (+ fused fc for b>0) ----------------
__global__ __launch_bounds__(256) void proj_kernel(
    const float* __restrict__ X, const float* __restrict__ Wl, const float* __restrict__ bl,
    const float* __restrict__ Wr, const float* __restrict__ br,
    const float* __restrict__ gbias, const float* __restrict__ Wfc, const float* __restrict__ bfc,
    float* __restrict__ gl0, float* __restrict__ gr0, unsigned short* __restrict__ xl){
  __shared__ float smem[2080 + 8320 + 8320];
  float* Xs  = smem;
  float* Wls = smem + 2080;
  float* R2  = smem + 2080 + 8320;
  int tid = threadIdx.x, blk = blockIdx.x;
  int g = blk & 7, t = (blk >> 3) & 63, b = blk >> 9;

  const float* Xp = X + ((size_t)(b*T_ + t)*N_ + g*32)*F_;
  for (int idx = tid; idx < 2048; idx += 256){
    int n = idx >> 6, k = idx & 63;
    Xs[n*65 + k] = Xp[idx];
  }
  for (int idx = tid; idx < 8192; idx += 256){
    int c = idx >> 6, k = idx & 63;
    Wls[c*65 + k] = Wl[idx];
  }
  if (b == 0){
    for (int idx = tid; idx < 8192; idx += 256){
      int c = idx >> 6, k = idx & 63;
      R2[c*65 + k] = Wr[idx];
    }
  } else {
    for (int idx = tid; idx < 4096; idx += 256){
      int o = idx >> 7, c = idx & 127;
      R2[4128 + o*129 + c] = Wfc[idx];
    }
  }
  __syncthreads();

  int c = tid & 127, nb = (tid >> 7) * 16;
  if (b == 0){
    float accL[16], accR[16];
    float blv = bl[c], brv = br[c];
    #pragma unroll
    for (int p = 0; p < 16; ++p){ accL[p] = blv; accR[p] = brv; }
    for (int k = 0; k < 64; ++k){
      float wl = Wls[c*65 + k], wr = R2[c*65 + k];
      #pragma unroll
      for (int p = 0; p < 16; ++p){
        float xv = Xs[(nb+p)*65 + k];
        accL[p] = fmaf(wl, xv, accL[p]);
        accR[p] = fmaf(wr, xv, accR[p]);
      }
    }
    size_t base = ((size_t)t*N_ + g*32)*C_;
    #pragma unroll
    for (int p = 0; p < 16; ++p){
      gl0[base + (size_t)(nb+p)*C_ + c] = accL[p];
      gr0[base + (size_t)(nb+p)*C_ + c] = accR[p];
    }
  } else {
    float accL[16];
    float blv = bl[c];
    #pragma unroll
    for (int p = 0; p < 16; ++p) accL[p] = blv;
    for (int k = 0; k < 64; ++k){
      float wl = Wls[c*65 + k];
      #pragma unroll
      for (int p = 0; p < 16; ++p)
        accL[p] = fmaf(wl, Xs[(nb+p)*65 + k], accL[p]);
    }
    float* gls = R2;
    float gbv = gbias[c];
    #pragma unroll
    for (int p = 0; p < 16; ++p) gls[(nb+p)*129 + c] = accL[p] + gbv;
    __syncthreads();
    float* Wfcs = R2 + 4128;
    int o = tid & 31, n2b = tid >> 5;
    float bfv = bfc[o];
    for (int p = 0; p < 4; ++p){
      int n2 = n2b + 8*p;
      float acc = bfv;
      for (int cc = 0; cc < 128; ++cc)
        acc = fmaf(gls[n2*129 + cc], Wfcs[o*129 + cc], acc);
      xl[((size_t)(b*T_ + t)*N_ + g*32 + n2)*O_ + o] = f2bf(acc);
    }
  }
}

// ---------------- K2: attention for b==0 (+ fused fc) ----------------
__global__ __launch_bounds__(256) void attn_kernel(
    const float* __restrict__ gl0, const float* __restrict__ gr0,
    const float* __restrict__ attr, const float* __restrict__ we, const float* __restrict__ att,
    const float* __restrict__ gbias, const float* __restrict__ Wfc, const float* __restrict__ bfc,
    unsigned short* __restrict__ xl){
  __shared__ float gls[32*129], grs[32*129], os_[32*129], Wfcs[32*129];
  __shared__ float ae[32*33], Ss[32*33];
  __shared__ float wes[128], atts[128];
  int tid = threadIdx.x, blk = blockIdx.x;
  int g = blk & 7, t = blk >> 3;

  const float* glp = gl0 + ((size_t)t*N_ + g*32)*C_;
  const float* grp = gr0 + ((size_t)t*N_ + g*32)*C_;
  for (int idx = tid; idx < 4096; idx += 256){
    int n = idx >> 7, c = idx & 127;
    gls[n*129 + c]  = glp[idx];
    grs[n*129 + c]  = grp[idx];
    Wfcs[n*129 + c] = Wfc[idx];
  }
  for (int idx = tid; idx < 1024; idx += 256) ae[(idx>>5)*33 + (idx&31)] = attr[g*1024 + idx];
  if (tid < 128){ wes[tid] = we[tid]; atts[tid] = att[tid]; }
  __syncthreads();

  int i = tid >> 3, jb = (tid & 7) * 4;
  float a0 = ae[(jb+0)*33 + i], a1 = ae[(jb+1)*33 + i], a2 = ae[(jb+2)*33 + i], a3 = ae[(jb+3)*33 + i];
  float s0 = 0.f, s1 = 0.f, s2 = 0.f, s3 = 0.f;
  for (int cc = 0; cc < 128; ++cc){
    float grv = grs[i*129 + cc];
    float wv = wes[cc], av = atts[cc];
    float p0 = gls[(jb+0)*129 + cc] + grv + a0*wv;
    float p1 = gls[(jb+1)*129 + cc] + grv + a1*wv;
    float p2 = gls[(jb+2)*129 + cc] + grv + a2*wv;
    float p3 = gls[(jb+3)*129 + cc] + grv + a3*wv;
    p0 = p0 > 0.f ? p0 : 0.2f*p0;
    p1 = p1 > 0.f ? p1 : 0.2f*p1;
    p2 = p2 > 0.f ? p2 : 0.2f*p2;
    p3 = p3 > 0.f ? p3 : 0.2f*p3;
    s0 = fmaf(p0, av, s0); s1 = fmaf(p1, av, s1);
    s2 = fmaf(p2, av, s2); s3 = fmaf(p3, av, s3);
  }
  Ss[i*33 + jb + 0] = s0; Ss[i*33 + jb + 1] = s1;
  Ss[i*33 + jb + 2] = s2; Ss[i*33 + jb + 3] = s3;
  __syncthreads();

  if (tid < 32){
    float mx = -1e30f;
    for (int j = 0; j < 32; ++j) mx = fmaxf(mx, Ss[tid*33 + j]);
    float sum = 0.f;
    for (int j = 0; j < 32; ++j) sum += expf(Ss[tid*33 + j] - mx);
    float inv = 1.f / sum;
    for (int j = 0; j < 32; ++j) Ss[tid*33 + j] = expf(Ss[tid*33 + j] - mx) * inv;
  }
  __syncthreads();

  int c2 = tid & 127, ibase = (tid >> 7) * 16;
  float gbv = gbias[c2];
  for (int p = 0; p < 16; ++p){
    int ii = ibase + p;
    float acc = 0.f;
    #pragma unroll
    for (int j = 0; j < 32; ++j) acc = fmaf(Ss[ii*33 + j], gls[j*129 + c2], acc);
    os_[ii*129 + c2] = acc + gbv;
  }
  __syncthreads();

  int o = tid & 31, n2b = tid >> 5;
  float bfv = bfc[o];
  for (int p = 0; p < 4; ++p){
    int n2 = n2b + 8*p;
    float acc = bfv;
    for (int cc = 0; cc < 128; ++cc)
      acc = fmaf(os_[n2*129 + cc], Wfcs[o*129 + cc], acc);
    xl[((size_t)t*N_ + g*32 + n2)*O_ + o] = f2bf(acc);   // b == 0
  }
}

// ---------------- fp32 -> bf16 conversion ----------------
__global__ __launch_bounds__(256) void f2b_kernel(const float* __restrict__ in,
                                                  unsigned short* __restrict__ out, int n4){
  int idx = blockIdx.x*256 + threadIdx.x;
  if (idx >= n4) return;
  float4 v = ((const float4*)in)[idx];
  ushort4 o;
  o.x = f2bf(v.x); o.y = f2bf(v.y); o.z = f2bf(v.z); o.w = f2bf(v.w);
  ((ushort4*)out)[idx] = o;
}

// ---------------- bf16 MFMA GEMM: Y = A @ W^T + b1 + b2 ----------------
// A: M x K bf16 row-major, W: N x K bf16 row-major, Y: M x N fp32. M=512 fixed by grid.
__global__ __launch_bounds__(256) void gemm_bf(
    const unsigned short* __restrict__ A, const unsigned short* __restrict__ W,
    const float* __restrict__ b1, const float* __restrict__ b2,
    float* __restrict__ Y, int N, int K){
  __shared__ __align__(16) short As[64*72];
  __shared__ __align__(16) short Bs[64*72];
  int tid = threadIdx.x;
  int m0 = blockIdx.x * 64, n0 = blockIdx.y * 64;
  int lane = tid & 63, w = tid >> 6;
  int wr = w >> 1, wc = w & 1;
  f32x4 zero = {0.f, 0.f, 0.f, 0.f};
  f32x4 acc[2][2] = {{zero, zero}, {zero, zero}};
  int lrow = lane & 15, koff = (lane >> 4) * 8;

  for (int kc = 0; kc < K; kc += 64){
    #pragma unroll
    for (int it = 0; it < 2; ++it){
      int chunk = tid + it*256;
      int r = chunk >> 3, cidx = chunk & 7;
      *(bf16x8*)&As[r*72 + cidx*8] = *(const bf16x8*)&A[(size_t)(m0 + r)*K + kc + cidx*8];
      *(bf16x8*)&Bs[r*72 + cidx*8] = *(const bf16x8*)&W[(size_t)(n0 + r)*K + kc + cidx*8];
    }
    __syncthreads();
    #pragma unroll
    for (int kk = 0; kk < 2; ++kk){
      bf16x8 a0 = *(const bf16x8*)&As[(wr*32 + 0*16 + lrow)*72 + kk*32 + koff];
      bf16x8 a1 = *(const bf16x8*)&As[(wr*32 + 1*16 + lrow)*72 + kk*32 + koff];
      bf16x8 bv0 = *(const bf16x8*)&Bs[(wc*32 + 0*16 + lrow)*72 + kk*32 + koff];
      bf16x8 bv1 = *(const bf16x8*)&Bs[(wc*32 + 1*16 + lrow)*72 + kk*32 + koff];
      acc[0][0] = __builtin_amdgcn_mfma_f32_16x16x32_bf16(a0, bv0, acc[0][0], 0, 0, 0);
      acc[0][1] = __builtin_amdgcn_mfma_f32_16x16x32_bf16(a0, bv1, acc[0][1], 0, 0, 0);
      acc[1][0] = __builtin_amdgcn_mfma_f32_16x16x32_bf16(a1, bv0, acc[1][0], 0, 0, 0);
      acc[1][1] = __builtin_amdgcn_mfma_f32_16x16x32_bf16(a1, bv1, acc[1][1], 0, 0, 0);
    }
    __syncthreads();
  }
  #pragma unroll
  for (int m = 0; m < 2; ++m)
    #pragma unroll
    for (int n = 0; n < 2; ++n)
      #pragma unroll
      for (int v = 0; v < 4; ++v){
        int rowi = wr*32 + m*16 + (lane>>4)*4 + v;
        int coli = wc*32 + n*16 + (lane&15);
        int gn = n0 + coli;
        Y[(size_t)(m0 + rowi)*N + gn] = acc[m][n][v] + b1[gn] + b2[gn];
      }
}

// ---------------- LSTM timestep (512 blocks, k-split + shfl reduce) ----------------
// block bl owns dims {bl*2, bl*2+1} x 4 gates = 8 rows of Whh. 256 thr = 8 rows x 32 ksplit.
__global__ __launch_bounds__(256) void lstm_step2(
    const float* __restrict__ Whh, const float* __restrict__ xg,
    float* __restrict__ h_seq, float* __restrict__ c_buf, int t){
  __shared__ float hs[8*1024];
  __shared__ float gsum[64];
  int tid = threadIdx.x;
  int dim0 = blockIdx.x * 2;
  if (t > 0){
    #pragma unroll
    for (int i = 0; i < 8; ++i){
      int chunk = tid + i*256;
      int b = chunk >> 8, k4 = (chunk & 255) * 4;
      float4 v = *(const float4*)&h_seq[((size_t)b*T_ + (t-1))*H_ + k4];
      int ksw = k4 ^ (((k4 >> 5) & 7) << 2);     // XOR-swizzle: spread stride-128B reads
      *(float4*)&hs[b*1024 + ksw] = v;
    }
  }
  __syncthreads();

  int r_loc = tid >> 5, ks = tid & 31;
  int q = r_loc >> 1, dloc = r_loc & 1;
  int row = q*H_ + dim0 + dloc;
  float acc[8] = {0.f,0.f,0.f,0.f,0.f,0.f,0.f,0.f};
  if (t > 0){
    const float4* wp = (const float4*)(Whh + (size_t)row*H_ + ks*32);
    float4 wv[8];
    #pragma unroll
    for (int i = 0; i < 8; ++i) wv[i] = wp[i];
    #pragma unroll
    for (int i = 0; i < 8; ++i){
      int ksw = (ks*32 + i*4) ^ ((ks & 7) << 2);
      #pragma unroll
      for (int b = 0; b < 8; ++b){
        float4 h = *(const float4*)&hs[b*1024 + ksw];
        acc[b] = fmaf(wv[i].x, h.x, acc[b]);
        acc[b] = fmaf(wv[i].y, h.y, acc[b]);
        acc[b] = fmaf(wv[i].z, h.z, acc[b]);
        acc[b] = fmaf(wv[i].w, h.w, acc[b]);
      }
    }
  }
  #pragma unroll
  for (int b = 0; b < 8; ++b){
    float v = acc[b];
    v += __shfl_xor(v, 16);
    v += __shfl_xor(v, 8);
    v += __shfl_xor(v, 4);
    v += __shfl_xor(v, 2);
    v += __shfl_xor(v, 1);
    if (ks == 0) gsum[r_loc*8 + b] = v;
  }
  __syncthreads();
  if (tid < 16){
    int b = tid >> 1, dl = tid & 1;
    int dim = dim0 + dl;
    size_t xbase = ((size_t)b*T_ + t)*4096;
    float iv = gsum[(0*2+dl)*8 + b] + xg[xbase + 0*H_ + dim];
    float fv = gsum[(1*2+dl)*8 + b] + xg[xbase + 1*H_ + dim];
    float gv = gsum[(2*2+dl)*8 + b] + xg[xbase + 2*H_ + dim];
    float ov = gsum[(3*2+dl)*8 + b] + xg[xbase + 3*H_ + dim];
    float i_ = sigf(iv), f_ = sigf(fv), g_ = tanhf(gv), o_ = sigf(ov);
    float cp = (t == 0) ? 0.f : c_buf[(size_t)b*H_ + dim];
    float cn = fmaf(f_, cp, i_*g_);
    float hn = o_ * tanhf(cn);
    c_buf[(size_t)b*H_ + dim] = cn;
    h_seq[((size_t)b*T_ + t)*H_ + dim] = hn;
  }
}

// ---------------- final head ----------------
__global__ __launch_bounds__(128) void final_kernel(
    const float* __restrict__ h2_seq, const float* __restrict__ Wout,
    const float* __restrict__ bout, float* __restrict__ out){
  int tid = threadIdx.x;
  int b = tid >> 4, nc = tid & 15;
  const float* hp = h2_seq + ((size_t)b*T_ + (T_ - 1))*H_;
  const float* wp = Wout + nc*H_;
  float acc = bout[nc];
  for (int k = 0; k < 1024; ++k) acc = fmaf(hp[k], wp[k], acc);
  out[tid] = acc;
}

extern "C" void kernel_launch(void* const* d_in, const int* in_sizes, int n_in,
                              void* d_out, int out_size, void* d_ws, size_t ws_size,
                              hipStream_t stream){
  const float* X    = (const float*)d_in[0];
  const float* V    = (const float*)d_in[1];
  const float* Wl   = (const float*)d_in[2];
  const float* bl   = (const float*)d_in[3];
  const float* Wr   = (const float*)d_in[4];
  const float* br   = (const float*)d_in[5];
  const float* att  = (const float*)d_in[6];
  const float* we   = (const float*)d_in[7];
  const float* gb   = (const float*)d_in[8];
  const float* Wfc  = (const float*)d_in[9];
  const float* bfc  = (const float*)d_in[10];
  const float* Wih0 = (const float*)d_in[11];
  const float* Whh0 = (const float*)d_in[12];
  const float* bih0 = (const float*)d_in[13];
  const float* bhh0 = (const float*)d_in[14];
  const float* Wih1 = (const float*)d_in[15];
  const float* Whh1 = (const float*)d_in[16];
  const float* bih1 = (const float*)d_in[17];
  const float* bhh1 = (const float*)d_in[18];
  const float* Wout = (const float*)d_in[19];
  const float* bout = (const float*)d_in[20];

  float* ws   = (float*)d_ws;
  float* attr = ws;                     // 8192
  float* gl0  = attr + 8192;            // 2097152
  float* gr0  = gl0 + 2097152;          // 2097152
  float* xg0  = gr0 + 2097152;          // 2097152
  float* xg1  = xg0 + 2097152;          // 2097152
  float* hseq = xg1 + 2097152;          // 524288
  float* h2sq = hseq + 524288;          // 524288
  float* c0   = h2sq + 524288;          // 8192
  float* c1   = c0 + 8192;              // 8192
  unsigned short* xl_bf = (unsigned short*)(c1 + 8192);   // 4194304 bf16
  unsigned short* w0_bf = xl_bf + 4194304;                // 33554432 bf16
  unsigned short* w1_bf = w0_bf + 33554432;               // 4194304 bf16
  unsigned short* hs_bf = w1_bf + 4194304;                // 524288 bf16
  (void)in_sizes; (void)n_in; (void)out_size; (void)ws_size;

  attr_kernel<<<8, 256, 0, stream>>>(V, attr);
  proj_kernel<<<4096, 256, 0, stream>>>(X, Wl, bl, Wr, br, gb, Wfc, bfc, gl0, gr0, xl_bf);
  attn_kernel<<<512, 256, 0, stream>>>(gl0, gr0, attr, we, att, gb, Wfc, bfc, xl_bf);

  f2b_kernel<<<32768, 256, 0, stream>>>(Wih0, w0_bf, 8388608);
  f2b_kernel<<<4096, 256, 0, stream>>>(Wih1, w1_bf, 1048576);

  gemm_bf<<<dim3(8, 64), 256, 0, stream>>>(xl_bf, w0_bf, bih0, bhh0, xg0, 4096, 8192);
  for (int t = 0; t < 64; ++t)
    lstm_step2<<<512, 256, 0, stream>>>(Whh0, xg0, hseq, c0, t);

  f2b_kernel<<<512, 256, 0, stream>>>(hseq, hs_bf, 131072);
  gemm_bf<<<dim3(8, 64), 256, 0, stream>>>(hs_bf, w1_bf, bih1, bhh1, xg1, 4096, 1024);
  for (int t = 0; t < 64; ++t)
    lstm_step2<<<512, 256, 0, stream>>>(Whh1, xg1, h2sq, c1, t);

  final_kernel<<<1, 128, 0, stream>>>(h2sq, Wout, bout, (float*)d_out);
}

// Round 3
// 1025.185 us; speedup vs baseline: 5.3765x; 1.3591x over previous
//
#include <hip/hip_runtime.h>
#include <cmath>

#define B_ 8
#define T_ 64
#define N_ 256
#define F_ 64
#define C_ 128
#define O_ 32
#define H_ 1024
#define NC_ 16

typedef __attribute__((ext_vector_type(8))) short bf16x8;
typedef __attribute__((ext_vector_type(4))) float f32x4;

__device__ __forceinline__ float sigf(float x){ return 1.f/(1.f+expf(-x)); }

__device__ __forceinline__ unsigned short f2bf(float f){
  unsigned int u = __float_as_uint(f);
  u += 0x7fff + ((u >> 16) & 1);          // round-to-nearest-even
  return (unsigned short)(u >> 16);
}
__device__ __forceinline__ float bf2f(unsigned short s){
  return __uint_as_float(((unsigned int)s) << 16);
}

__device__ __forceinline__ void gload16(const void* g, void* l){
  __builtin_amdgcn_global_load_lds((const __attribute__((address_space(1))) void*)g,
                                   (__attribute__((address_space(3))) void*)l, 16, 0, 0);
}

// ---------------- K0: attr_eff[g][j][i] ----------------
__global__ __launch_bounds__(256) void attr_kernel(const float* __restrict__ V, float* __restrict__ attr){
  __shared__ float sv[32][33];
  __shared__ float selfv[32];
  int g = blockIdx.x, tid = threadIdx.x;
  for (int idx = tid; idx < 1024; idx += 256){
    int j = idx >> 5, i = idx & 31;
    sv[j][i] = sigf(V[(size_t)(g*32 + j)*256 + g*32 + i]);
  }
  __syncthreads();
  if (tid < 32){
    float s = 0.f;
    for (int j = 0; j < 32; ++j) if (j != tid) s += sv[j][tid];
    selfv[tid] = s * (1.f/31.f);
  }
  __syncthreads();
  for (int idx = tid; idx < 1024; idx += 256){
    int j = idx >> 5, i = idx & 31;
    attr[g*1024 + idx] = (j == i) ? selfv[i] : sv[j][i];
  }
}

// ---------------- K1: projections (+ fused fc for b>0) ----------------
__global__ __launch_bounds__(256) void proj_kernel(
    const float* __restrict__ X, const float* __restrict__ Wl, const float* __restrict__ bl,
    const float* __restrict__ Wr, const float* __restrict__ br,
    const float* __restrict__ gbias, const float* __restrict__ Wfc, const float* __restrict__ bfc,
    float* __restrict__ gl0, float* __restrict__ gr0, unsigned short* __restrict__ xl){
  __shared__ float smem[2080 + 8320 + 8320];
  float* Xs  = smem;
  float* Wls = smem + 2080;
  float* R2  = smem + 2080 + 8320;
  int tid = threadIdx.x, blk = blockIdx.x;
  int g = blk & 7, t = (blk >> 3) & 63, b = blk >> 9;

  const float* Xp = X + ((size_t)(b*T_ + t)*N_ + g*32)*F_;
  for (int idx = tid; idx < 2048; idx += 256){
    int n = idx >> 6, k = idx & 63;
    Xs[n*65 + k] = Xp[idx];
  }
  for (int idx = tid; idx < 8192; idx += 256){
    int c = idx >> 6, k = idx & 63;
    Wls[c*65 + k] = Wl[idx];
  }
  if (b == 0){
    for (int idx = tid; idx < 8192; idx += 256){
      int c = idx >> 6, k = idx & 63;
      R2[c*65 + k] = Wr[idx];
    }
  } else {
    for (int idx = tid; idx < 4096; idx += 256){
      int o = idx >> 7, c = idx & 127;
      R2[4128 + o*129 + c] = Wfc[idx];
    }
  }
  __syncthreads();

  int c = tid & 127, nb = (tid >> 7) * 16;
  if (b == 0){
    float accL[16], accR[16];
    float blv = bl[c], brv = br[c];
    #pragma unroll
    for (int p = 0; p < 16; ++p){ accL[p] = blv; accR[p] = brv; }
    for (int k = 0; k < 64; ++k){
      float wl = Wls[c*65 + k], wr = R2[c*65 + k];
      #pragma unroll
      for (int p = 0; p < 16; ++p){
        float xv = Xs[(nb+p)*65 + k];
        accL[p] = fmaf(wl, xv, accL[p]);
        accR[p] = fmaf(wr, xv, accR[p]);
      }
    }
    size_t base = ((size_t)t*N_ + g*32)*C_;
    #pragma unroll
    for (int p = 0; p < 16; ++p){
      gl0[base + (size_t)(nb+p)*C_ + c] = accL[p];
      gr0[base + (size_t)(nb+p)*C_ + c] = accR[p];
    }
  } else {
    float accL[16];
    float blv = bl[c];
    #pragma unroll
    for (int p = 0; p < 16; ++p) accL[p] = blv;
    for (int k = 0; k < 64; ++k){
      float wl = Wls[c*65 + k];
      #pragma unroll
      for (int p = 0; p < 16; ++p)
        accL[p] = fmaf(wl, Xs[(nb+p)*65 + k], accL[p]);
    }
    float* gls = R2;
    float gbv = gbias[c];
    #pragma unroll
    for (int p = 0; p < 16; ++p) gls[(nb+p)*129 + c] = accL[p] + gbv;
    __syncthreads();
    float* Wfcs = R2 + 4128;
    int o = tid & 31, n2b = tid >> 5;
    float bfv = bfc[o];
    for (int p = 0; p < 4; ++p){
      int n2 = n2b + 8*p;
      float acc = bfv;
      for (int cc = 0; cc < 128; ++cc)
        acc = fmaf(gls[n2*129 + cc], Wfcs[o*129 + cc], acc);
      xl[((size_t)(b*T_ + t)*N_ + g*32 + n2)*O_ + o] = f2bf(acc);
    }
  }
}

// ---------------- K2: attention for b==0 (+ fused fc) ----------------
__global__ __launch_bounds__(256) void attn_kernel(
    const float* __restrict__ gl0, const float* __restrict__ gr0,
    const float* __restrict__ attr, const float* __restrict__ we, const float* __restrict__ att,
    const float* __restrict__ gbias, const float* __restrict__ Wfc, const float* __restrict__ bfc,
    unsigned short* __restrict__ xl){
  __shared__ float gls[32*129], grs[32*129], os_[32*129], Wfcs[32*129];
  __shared__ float ae[32*33], Ss[32*33];
  __shared__ float wes[128], atts[128];
  int tid = threadIdx.x, blk = blockIdx.x;
  int g = blk & 7, t = blk >> 3;

  const float* glp = gl0 + ((size_t)t*N_ + g*32)*C_;
  const float* grp = gr0 + ((size_t)t*N_ + g*32)*C_;
  for (int idx = tid; idx < 4096; idx += 256){
    int n = idx >> 7, c = idx & 127;
    gls[n*129 + c]  = glp[idx];
    grs[n*129 + c]  = grp[idx];
    Wfcs[n*129 + c] = Wfc[idx];
  }
  for (int idx = tid; idx < 1024; idx += 256) ae[(idx>>5)*33 + (idx&31)] = attr[g*1024 + idx];
  if (tid < 128){ wes[tid] = we[tid]; atts[tid] = att[tid]; }
  __syncthreads();

  int i = tid >> 3, jb = (tid & 7) * 4;
  float a0 = ae[(jb+0)*33 + i], a1 = ae[(jb+1)*33 + i], a2 = ae[(jb+2)*33 + i], a3 = ae[(jb+3)*33 + i];
  float s0 = 0.f, s1 = 0.f, s2 = 0.f, s3 = 0.f;
  for (int cc = 0; cc < 128; ++cc){
    float grv = grs[i*129 + cc];
    float wv = wes[cc], av = atts[cc];
    float p0 = gls[(jb+0)*129 + cc] + grv + a0*wv;
    float p1 = gls[(jb+1)*129 + cc] + grv + a1*wv;
    float p2 = gls[(jb+2)*129 + cc] + grv + a2*wv;
    float p3 = gls[(jb+3)*129 + cc] + grv + a3*wv;
    p0 = p0 > 0.f ? p0 : 0.2f*p0;
    p1 = p1 > 0.f ? p1 : 0.2f*p1;
    p2 = p2 > 0.f ? p2 : 0.2f*p2;
    p3 = p3 > 0.f ? p3 : 0.2f*p3;
    s0 = fmaf(p0, av, s0); s1 = fmaf(p1, av, s1);
    s2 = fmaf(p2, av, s2); s3 = fmaf(p3, av, s3);
  }
  Ss[i*33 + jb + 0] = s0; Ss[i*33 + jb + 1] = s1;
  Ss[i*33 + jb + 2] = s2; Ss[i*33 + jb + 3] = s3;
  __syncthreads();

  if (tid < 32){
    float mx = -1e30f;
    for (int j = 0; j < 32; ++j) mx = fmaxf(mx, Ss[tid*33 + j]);
    float sum = 0.f;
    for (int j = 0; j < 32; ++j) sum += expf(Ss[tid*33 + j] - mx);
    float inv = 1.f / sum;
    for (int j = 0; j < 32; ++j) Ss[tid*33 + j] = expf(Ss[tid*33 + j] - mx) * inv;
  }
  __syncthreads();

  int c2 = tid & 127, ibase = (tid >> 7) * 16;
  float gbv = gbias[c2];
  for (int p = 0; p < 16; ++p){
    int ii = ibase + p;
    float acc = 0.f;
    #pragma unroll
    for (int j = 0; j < 32; ++j) acc = fmaf(Ss[ii*33 + j], gls[j*129 + c2], acc);
    os_[ii*129 + c2] = acc + gbv;
  }
  __syncthreads();

  int o = tid & 31, n2b = tid >> 5;
  float bfv = bfc[o];
  for (int p = 0; p < 4; ++p){
    int n2 = n2b + 8*p;
    float acc = bfv;
    for (int cc = 0; cc < 128; ++cc)
      acc = fmaf(os_[n2*129 + cc], Wfcs[o*129 + cc], acc);
    xl[((size_t)t*N_ + g*32 + n2)*O_ + o] = f2bf(acc);   // b == 0
  }
}

// ---------------- fp32 -> bf16 conversion ----------------
__global__ __launch_bounds__(256) void f2b_kernel(const float* __restrict__ in,
                                                  unsigned short* __restrict__ out, int n4){
  int idx = blockIdx.x*256 + threadIdx.x;
  if (idx >= n4) return;
  float4 v = ((const float4*)in)[idx];
  ushort4 o;
  o.x = f2bf(v.x); o.y = f2bf(v.y); o.z = f2bf(v.z); o.w = f2bf(v.w);
  ((ushort4*)out)[idx] = o;
}

// ---------------- bf16 MFMA GEMM: Y = A @ W^T + b1 + b2 ----------------
// A: 512 x K bf16, W: N x K bf16, Y: 512 x N fp32. Tile 64(M) x 128(N), BK=64.
// grid flat 256, XCD-swizzled. global_load_lds staging, XOR-swizzled LDS.
__global__ __launch_bounds__(256) void gemm_bf2(
    const unsigned short* __restrict__ A, const unsigned short* __restrict__ W,
    const float* __restrict__ b1, const float* __restrict__ b2,
    float* __restrict__ Y, int N, int K){
  __shared__ __align__(16) short As[2][64*64];
  __shared__ __align__(16) short Bs[2][128*64];
  int tid = threadIdx.x;
  int id = blockIdx.x;
  int xcd = id & 7, local = id >> 3;
  int nt = xcd*4 + (local & 3), mt = local >> 2;   // bijective: XCD owns 4 n-tiles
  int m0 = mt*64, n0 = nt*128;
  int lane = tid & 63;
  int w = tid >> 6, wm = w >> 1, wn = w & 1;
  int lr = lane & 15, ko = lane >> 4;
  int wbase = tid & ~63;

  auto STAGE = [&](int buf, int kc){
    #pragma unroll
    for (int it = 0; it < 2; ++it){
      int chunk = it*256 + tid;
      int r = chunk >> 3, c8 = chunk & 7;
      int cs = (c8 ^ (r & 7)) << 3;
      gload16(&A[(size_t)(m0 + r)*K + kc + cs], &As[buf][(size_t)(it*256 + wbase)*8]);
    }
    #pragma unroll
    for (int it = 0; it < 4; ++it){
      int chunk = it*256 + tid;
      int r = chunk >> 3, c8 = chunk & 7;
      int cs = (c8 ^ (r & 7)) << 3;
      gload16(&W[(size_t)(n0 + r)*K + kc + cs], &Bs[buf][(size_t)(it*256 + wbase)*8]);
    }
  };

  f32x4 zero = {0.f,0.f,0.f,0.f};
  f32x4 acc[2][4] = {{zero,zero,zero,zero},{zero,zero,zero,zero}};

  STAGE(0, 0);
  __syncthreads();                       // implicit vmcnt(0): buf0 ready
  int nk = K >> 6;
  for (int kt = 0; kt < nk; ++kt){
    int cur = kt & 1;
    if (kt + 1 < nk) STAGE(cur ^ 1, (kt + 1) << 6);   // issue next tile first
    #pragma unroll
    for (int kk = 0; kk < 2; ++kk){
      int s = kk*4 + ko;
      bf16x8 af[2], bfv[4];
      #pragma unroll
      for (int m = 0; m < 2; ++m){
        int row = wm*32 + m*16 + lr;
        af[m] = *(const bf16x8*)&As[cur][row*64 + ((s ^ (row & 7)) << 3)];
      }
      #pragma unroll
      for (int n = 0; n < 4; ++n){
        int row = wn*64 + n*16 + lr;
        bfv[n] = *(const bf16x8*)&Bs[cur][row*64 + ((s ^ (row & 7)) << 3)];
      }
      #pragma unroll
      for (int m = 0; m < 2; ++m)
        #pragma unroll
        for (int n = 0; n < 4; ++n)
          acc[m][n] = __builtin_amdgcn_mfma_f32_16x16x32_bf16(af[m], bfv[n], acc[m][n], 0, 0, 0);
    }
    __syncthreads();                     // drains next-tile stage + barrier
  }

  #pragma unroll
  for (int m = 0; m < 2; ++m)
    #pragma unroll
    for (int n = 0; n < 4; ++n)
      #pragma unroll
      for (int v = 0; v < 4; ++v){
        int row = m0 + wm*32 + m*16 + ko*4 + v;
        int col = n0 + wn*64 + n*16 + lr;
        Y[(size_t)row*N + col] = acc[m][n][v] + b1[col] + b2[col];
      }
}

// ---------------- LSTM timestep via MFMA ----------------
// 256 blocks; block owns dims [dim0, dim0+4) x 4 gates = 16 Whh rows (B-operand, N=16).
// M=16 holds 8 batches (+8 pad). K=1024 split over 4 waves, LDS reduce, fused gates.
__global__ __launch_bounds__(256) void lstm_mfma(
    const unsigned short* __restrict__ whh,   // [4096][1024] bf16
    const float* __restrict__ xg,             // [B][T][4096] fp32
    unsigned short* __restrict__ hseq,        // [B][T][1024] bf16
    float* __restrict__ c_buf,                // [B][1024] fp32
    int t){
  __shared__ float red[4][64][4];
  __shared__ float pre[8][17];
  int tid = threadIdx.x;
  int lane = tid & 63, w = tid >> 6;
  int dim0 = blockIdx.x * 4;

  f32x4 acc = {0.f,0.f,0.f,0.f};
  if (t > 0){
    int lr = lane & 15, ko = lane >> 4;
    int q = lr >> 2, dl = lr & 3;
    const unsigned short* wrow = &whh[(size_t)(q*H_ + dim0 + dl)*H_];
    const unsigned short* hrow = &hseq[((size_t)(lr & 7)*T_ + (t-1))*H_];
    bf16x8 zero8 = {0,0,0,0,0,0,0,0};
    f32x4 acc2 = {0.f,0.f,0.f,0.f};
    #pragma unroll
    for (int kk = 0; kk < 8; ++kk){
      int kbase = w*256 + kk*32 + ko*8;
      bf16x8 bv = *(const bf16x8*)&wrow[kbase];
      bf16x8 av = (lr < 8) ? *(const bf16x8*)&hrow[kbase] : zero8;
      if (kk & 1) acc2 = __builtin_amdgcn_mfma_f32_16x16x32_bf16(av, bv, acc2, 0, 0, 0);
      else        acc  = __builtin_amdgcn_mfma_f32_16x16x32_bf16(av, bv, acc,  0, 0, 0);
    }
    acc = acc + acc2;
  }
  #pragma unroll
  for (int v = 0; v < 4; ++v) red[w][lane][v] = acc[v];
  __syncthreads();
  if (w == 0){
    float s0 = red[0][lane][0] + red[1][lane][0] + red[2][lane][0] + red[3][lane][0];
    float s1 = red[0][lane][1] + red[1][lane][1] + red[2][lane][1] + red[3][lane][1];
    float s2 = red[0][lane][2] + red[1][lane][2] + red[2][lane][2] + red[3][lane][2];
    float s3 = red[0][lane][3] + red[1][lane][3] + red[2][lane][3] + red[3][lane][3];
    if (lane < 32){
      int mb = (lane >> 4) * 4, n = lane & 15;
      pre[mb + 0][n] = s0;
      pre[mb + 1][n] = s1;
      pre[mb + 2][n] = s2;
      pre[mb + 3][n] = s3;
    }
  }
  __syncthreads();
  if (tid < 32){
    int b = tid >> 2, dl = tid & 3;
    int dim = dim0 + dl;
    size_t xb = ((size_t)b*T_ + t)*4096;
    float pi = pre[b][0 + dl]  + xg[xb + 0*H_ + dim];
    float pf = pre[b][4 + dl]  + xg[xb + 1*H_ + dim];
    float pg = pre[b][8 + dl]  + xg[xb + 2*H_ + dim];
    float po = pre[b][12 + dl] + xg[xb + 3*H_ + dim];
    float i_ = sigf(pi), f_ = sigf(pf), g_ = tanhf(pg), o_ = sigf(po);
    float cp = (t > 0) ? c_buf[(size_t)b*H_ + dim] : 0.f;
    float cn = fmaf(f_, cp, i_*g_);
    float hn = o_ * tanhf(cn);
    c_buf[(size_t)b*H_ + dim] = cn;
    hseq[((size_t)b*T_ + t)*H_ + dim] = f2bf(hn);
  }
}

// ---------------- final head (bf16 h2) ----------------
__global__ __launch_bounds__(128) void final_kernel(
    const unsigned short* __restrict__ h2_seq, const float* __restrict__ Wout,
    const float* __restrict__ bout, float* __restrict__ out){
  int tid = threadIdx.x;
  int b = tid >> 4, nc = tid & 15;
  const unsigned short* hp = h2_seq + ((size_t)b*T_ + (T_ - 1))*H_;
  const float* wp = Wout + nc*H_;
  float acc = bout[nc];
  for (int k = 0; k < 1024; ++k) acc = fmaf(bf2f(hp[k]), wp[k], acc);
  out[tid] = acc;
}

extern "C" void kernel_launch(void* const* d_in, const int* in_sizes, int n_in,
                              void* d_out, int out_size, void* d_ws, size_t ws_size,
                              hipStream_t stream){
  const float* X    = (const float*)d_in[0];
  const float* V    = (const float*)d_in[1];
  const float* Wl   = (const float*)d_in[2];
  const float* bl   = (const float*)d_in[3];
  const float* Wr   = (const float*)d_in[4];
  const float* br   = (const float*)d_in[5];
  const float* att  = (const float*)d_in[6];
  const float* we   = (const float*)d_in[7];
  const float* gb   = (const float*)d_in[8];
  const float* Wfc  = (const float*)d_in[9];
  const float* bfc  = (const float*)d_in[10];
  const float* Wih0 = (const float*)d_in[11];
  const float* Whh0 = (const float*)d_in[12];
  const float* bih0 = (const float*)d_in[13];
  const float* bhh0 = (const float*)d_in[14];
  const float* Wih1 = (const float*)d_in[15];
  const float* Whh1 = (const float*)d_in[16];
  const float* bih1 = (const float*)d_in[17];
  const float* bhh1 = (const float*)d_in[18];
  const float* Wout = (const float*)d_in[19];
  const float* bout = (const float*)d_in[20];

  float* ws   = (float*)d_ws;
  float* attr = ws;                     // 8192
  float* gl0  = attr + 8192;            // 2097152
  float* gr0  = gl0 + 2097152;          // 2097152
  float* xg0  = gr0 + 2097152;          // 2097152
  float* xg1  = xg0 + 2097152;          // 2097152
  float* c0   = xg1 + 2097152;          // 8192
  float* c1   = c0 + 8192;              // 8192
  unsigned short* xl_bf  = (unsigned short*)(c1 + 8192);  // 4194304
  unsigned short* w0_bf  = xl_bf + 4194304;               // 33554432
  unsigned short* w1_bf  = w0_bf + 33554432;              // 4194304
  unsigned short* wh0_bf = w1_bf + 4194304;               // 4194304
  unsigned short* wh1_bf = wh0_bf + 4194304;              // 4194304
  unsigned short* h1_bf  = wh1_bf + 4194304;              // 524288
  unsigned short* h2_bf  = h1_bf + 524288;                // 524288
  (void)in_sizes; (void)n_in; (void)out_size; (void)ws_size;

  attr_kernel<<<8, 256, 0, stream>>>(V, attr);
  proj_kernel<<<4096, 256, 0, stream>>>(X, Wl, bl, Wr, br, gb, Wfc, bfc, gl0, gr0, xl_bf);
  attn_kernel<<<512, 256, 0, stream>>>(gl0, gr0, attr, we, att, gb, Wfc, bfc, xl_bf);

  f2b_kernel<<<32768, 256, 0, stream>>>(Wih0, w0_bf, 8388608);
  f2b_kernel<<<4096, 256, 0, stream>>>(Wih1, w1_bf, 1048576);
  f2b_kernel<<<4096, 256, 0, stream>>>(Whh0, wh0_bf, 1048576);
  f2b_kernel<<<4096, 256, 0, stream>>>(Whh1, wh1_bf, 1048576);

  gemm_bf2<<<256, 256, 0, stream>>>(xl_bf, w0_bf, bih0, bhh0, xg0, 4096, 8192);
  for (int t = 0; t < 64; ++t)
    lstm_mfma<<<256, 256, 0, stream>>>(wh0_bf, xg0, h1_bf, c0, t);

  gemm_bf2<<<256, 256, 0, stream>>>(h1_bf, w1_bf, bih1, bhh1, xg1, 4096, 1024);
  for (int t = 0; t < 64; ++t)
    lstm_mfma<<<256, 256, 0, stream>>>(wh1_bf, xg1, h2_bf, c1, t);

  final_kernel<<<1, 128, 0, stream>>>(h2_bf, Wout, bout, (float*)d_out);
}

// Round 4
// 844.201 us; speedup vs baseline: 6.5292x; 1.2144x over previous
//
#include <hip/hip_runtime.h>
#include <cmath>

#define B_ 8
#define T_ 64
#define N_ 256
#define F_ 64
#define C_ 128
#define O_ 32
#define H_ 1024
#define NC_ 16

typedef __attribute__((ext_vector_type(8))) short bf16x8;
typedef __attribute__((ext_vector_type(4))) float f32x4;

__device__ __forceinline__ float sigf(float x){ return 1.f/(1.f+expf(-x)); }

__device__ __forceinline__ unsigned short f2bf(float f){
  unsigned int u = __float_as_uint(f);
  u += 0x7fff + ((u >> 16) & 1);          // round-to-nearest-even
  return (unsigned short)(u >> 16);
}
__device__ __forceinline__ float bf2f(unsigned short s){
  return __uint_as_float(((unsigned int)s) << 16);
}

__device__ __forceinline__ void gload16(const void* g, void* l){
  __builtin_amdgcn_global_load_lds((const __attribute__((address_space(1))) void*)g,
                                   (__attribute__((address_space(3))) void*)l, 16, 0, 0);
}

// convert 8 consecutive fp32 at p -> bf16x8
__device__ __forceinline__ bf16x8 cvt8(const float* p){
  float4 a = *(const float4*)p, b = *(const float4*)(p + 4);
  bf16x8 r;
  r[0] = (short)f2bf(a.x); r[1] = (short)f2bf(a.y);
  r[2] = (short)f2bf(a.z); r[3] = (short)f2bf(a.w);
  r[4] = (short)f2bf(b.x); r[5] = (short)f2bf(b.y);
  r[6] = (short)f2bf(b.z); r[7] = (short)f2bf(b.w);
  return r;
}

// ---------------- K0: attr_eff[g][j][i] ----------------
__global__ __launch_bounds__(256) void attr_kernel(const float* __restrict__ V, float* __restrict__ attr){
  __shared__ float sv[32][33];
  __shared__ float selfv[32];
  int g = blockIdx.x, tid = threadIdx.x;
  for (int idx = tid; idx < 1024; idx += 256){
    int j = idx >> 5, i = idx & 31;
    sv[j][i] = sigf(V[(size_t)(g*32 + j)*256 + g*32 + i]);
  }
  __syncthreads();
  if (tid < 32){
    float s = 0.f;
    for (int j = 0; j < 32; ++j) if (j != tid) s += sv[j][tid];
    selfv[tid] = s * (1.f/31.f);
  }
  __syncthreads();
  for (int idx = tid; idx < 1024; idx += 256){
    int j = idx >> 5, i = idx & 31;
    attr[g*1024 + idx] = (j == i) ? selfv[i] : sv[j][i];
  }
}

// ---------------- prep: Wcomb = Wfc@Wl (bf16), bias_comb, Wlr_bf ----------------
__global__ __launch_bounds__(256) void prep_kernel(
    const float* __restrict__ Wl, const float* __restrict__ Wr,
    const float* __restrict__ bl, const float* __restrict__ gb,
    const float* __restrict__ Wfc, const float* __restrict__ bfc,
    unsigned short* __restrict__ wcomb,   // [32][64] bf16
    float* __restrict__ bias_comb,        // [32]
    unsigned short* __restrict__ wlr){    // [256][64] bf16 (Wl rows then Wr rows)
  __shared__ float wls[8192], wfcs[4096];
  int tid = threadIdx.x;
  for (int i = tid; i < 8192; i += 256) wls[i] = Wl[i];
  for (int i = tid; i < 4096; i += 256) wfcs[i] = Wfc[i];
  __syncthreads();
  for (int idx = tid; idx < 2048; idx += 256){
    int o = idx >> 6, f = idx & 63;
    float acc = 0.f;
    for (int c = 0; c < 128; ++c) acc = fmaf(wfcs[o*128 + c], wls[c*64 + f], acc);
    wcomb[idx] = f2bf(acc);
  }
  if (tid < 32){
    float acc = bfc[tid];
    for (int c = 0; c < 128; ++c) acc = fmaf(wfcs[tid*128 + c], bl[c] + gb[c], acc);
    bias_comb[tid] = acc;
  }
  for (int idx = tid; idx < 16384; idx += 256){
    int r = idx >> 6, f = idx & 63;
    wlr[idx] = f2bf(r < 128 ? wls[r*64 + f] : Wr[(r-128)*64 + f]);
  }
}

// ---------------- gemm_proj0: gl0/gr0 = X0 @ [Wl;Wr]^T (b==0 slice) ----------------
// M=16384 rows, K=64, N=256. grid 256 x 256thr (4 waves x 16 rows).
__global__ __launch_bounds__(256) void gemm_proj0(
    const float* __restrict__ X, const unsigned short* __restrict__ wlr,
    const float* __restrict__ bl, const float* __restrict__ br,
    float* __restrict__ gl0, float* __restrict__ gr0){
  int tid = threadIdx.x;
  int lane = tid & 63, w = tid >> 6;
  int lr = lane & 15, ko = lane >> 4;
  int row = blockIdx.x*64 + w*16 + lr;

  bf16x8 af[2];
  #pragma unroll
  for (int ks = 0; ks < 2; ++ks)
    af[ks] = cvt8(&X[(size_t)row*64 + ks*32 + ko*8]);

  f32x4 zero = {0.f,0.f,0.f,0.f};
  #pragma unroll 4
  for (int nt = 0; nt < 16; ++nt){
    f32x4 acc = zero;
    #pragma unroll
    for (int ks = 0; ks < 2; ++ks){
      bf16x8 bv = *(const bf16x8*)&wlr[(size_t)(nt*16 + lr)*64 + ks*32 + ko*8];
      acc = __builtin_amdgcn_mfma_f32_16x16x32_bf16(af[ks], bv, acc, 0, 0, 0);
    }
    int col = nt*16 + lr;
    #pragma unroll
    for (int v = 0; v < 4; ++v){
      int orow = blockIdx.x*64 + w*16 + ko*4 + v;
      if (col < 128) gl0[(size_t)orow*128 + col]        = acc[v] + bl[col];
      else           gr0[(size_t)orow*128 + (col-128)]  = acc[v] + br[col-128];
    }
  }
}

// ---------------- gemm_rest: xl(b>0) = X @ Wcomb^T + bias_comb ----------------
// M=114688 (rows 16384..), K=64, N=32. grid 448 x 256thr.
__global__ __launch_bounds__(256) void gemm_rest(
    const float* __restrict__ X, const unsigned short* __restrict__ wcomb,
    const float* __restrict__ bias_comb, unsigned short* __restrict__ xl){
  int tid = threadIdx.x;
  int lane = tid & 63, w = tid >> 6;
  int lr = lane & 15, ko = lane >> 4;
  int r0 = 16384 + blockIdx.x*256 + w*64;

  bf16x8 bv[2][2];
  #pragma unroll
  for (int nt = 0; nt < 2; ++nt)
    #pragma unroll
    for (int ks = 0; ks < 2; ++ks)
      bv[nt][ks] = *(const bf16x8*)&wcomb[(size_t)(nt*16 + lr)*64 + ks*32 + ko*8];

  f32x4 zero = {0.f,0.f,0.f,0.f};
  #pragma unroll
  for (int mt = 0; mt < 4; ++mt){
    int row = r0 + mt*16 + lr;
    bf16x8 af[2];
    #pragma unroll
    for (int ks = 0; ks < 2; ++ks)
      af[ks] = cvt8(&X[(size_t)row*64 + ks*32 + ko*8]);
    f32x4 acc0 = zero, acc1 = zero;
    #pragma unroll
    for (int ks = 0; ks < 2; ++ks){
      acc0 = __builtin_amdgcn_mfma_f32_16x16x32_bf16(af[ks], bv[0][ks], acc0, 0, 0, 0);
      acc1 = __builtin_amdgcn_mfma_f32_16x16x32_bf16(af[ks], bv[1][ks], acc1, 0, 0, 0);
    }
    #pragma unroll
    for (int v = 0; v < 4; ++v){
      int orow = r0 + mt*16 + ko*4 + v;
      xl[(size_t)orow*32 + lr]      = f2bf(acc0[v] + bias_comb[lr]);
      xl[(size_t)orow*32 + 16 + lr] = f2bf(acc1[v] + bias_comb[16 + lr]);
    }
  }
}

// ---------------- K2: attention for b==0 (+ fused fc) ----------------
__global__ __launch_bounds__(256) void attn_kernel(
    const float* __restrict__ gl0, const float* __restrict__ gr0,
    const float* __restrict__ attr, const float* __restrict__ we, const float* __restrict__ att,
    const float* __restrict__ gbias, const float* __restrict__ Wfc, const float* __restrict__ bfc,
    unsigned short* __restrict__ xl){
  __shared__ float gls[32*129], grs[32*129], os_[32*129], Wfcs[32*129];
  __shared__ float ae[32*33], Ss[32*33];
  __shared__ float wes[128], atts[128];
  int tid = threadIdx.x, blk = blockIdx.x;
  int g = blk & 7, t = blk >> 3;

  const float* glp = gl0 + ((size_t)t*N_ + g*32)*C_;
  const float* grp = gr0 + ((size_t)t*N_ + g*32)*C_;
  for (int idx = tid; idx < 4096; idx += 256){
    int n = idx >> 7, c = idx & 127;
    gls[n*129 + c]  = glp[idx];
    grs[n*129 + c]  = grp[idx];
    Wfcs[n*129 + c] = Wfc[idx];
  }
  for (int idx = tid; idx < 1024; idx += 256) ae[(idx>>5)*33 + (idx&31)] = attr[g*1024 + idx];
  if (tid < 128){ wes[tid] = we[tid]; atts[tid] = att[tid]; }
  __syncthreads();

  int i = tid >> 3, jb = (tid & 7) * 4;
  float a0 = ae[(jb+0)*33 + i], a1 = ae[(jb+1)*33 + i], a2 = ae[(jb+2)*33 + i], a3 = ae[(jb+3)*33 + i];
  float s0 = 0.f, s1 = 0.f, s2 = 0.f, s3 = 0.f;
  for (int cc = 0; cc < 128; ++cc){
    float grv = grs[i*129 + cc];
    float wv = wes[cc], av = atts[cc];
    float p0 = gls[(jb+0)*129 + cc] + grv + a0*wv;
    float p1 = gls[(jb+1)*129 + cc] + grv + a1*wv;
    float p2 = gls[(jb+2)*129 + cc] + grv + a2*wv;
    float p3 = gls[(jb+3)*129 + cc] + grv + a3*wv;
    p0 = p0 > 0.f ? p0 : 0.2f*p0;
    p1 = p1 > 0.f ? p1 : 0.2f*p1;
    p2 = p2 > 0.f ? p2 : 0.2f*p2;
    p3 = p3 > 0.f ? p3 : 0.2f*p3;
    s0 = fmaf(p0, av, s0); s1 = fmaf(p1, av, s1);
    s2 = fmaf(p2, av, s2); s3 = fmaf(p3, av, s3);
  }
  Ss[i*33 + jb + 0] = s0; Ss[i*33 + jb + 1] = s1;
  Ss[i*33 + jb + 2] = s2; Ss[i*33 + jb + 3] = s3;
  __syncthreads();

  if (tid < 32){
    float mx = -1e30f;
    for (int j = 0; j < 32; ++j) mx = fmaxf(mx, Ss[tid*33 + j]);
    float sum = 0.f;
    for (int j = 0; j < 32; ++j) sum += expf(Ss[tid*33 + j] - mx);
    float inv = 1.f / sum;
    for (int j = 0; j < 32; ++j) Ss[tid*33 + j] = expf(Ss[tid*33 + j] - mx) * inv;
  }
  __syncthreads();

  int c2 = tid & 127, ibase = (tid >> 7) * 16;
  float gbv = gbias[c2];
  for (int p = 0; p < 16; ++p){
    int ii = ibase + p;
    float acc = 0.f;
    #pragma unroll
    for (int j = 0; j < 32; ++j) acc = fmaf(Ss[ii*33 + j], gls[j*129 + c2], acc);
    os_[ii*129 + c2] = acc + gbv;
  }
  __syncthreads();

  int o = tid & 31, n2b = tid >> 5;
  float bfv = bfc[o];
  for (int p = 0; p < 4; ++p){
    int n2 = n2b + 8*p;
    float acc = bfv;
    for (int cc = 0; cc < 128; ++cc)
      acc = fmaf(os_[n2*129 + cc], Wfcs[o*129 + cc], acc);
    xl[((size_t)t*N_ + g*32 + n2)*O_ + o] = f2bf(acc);   // b == 0
  }
}

// ---------------- fp32 -> bf16 conversion ----------------
__global__ __launch_bounds__(256) void f2b_kernel(const float* __restrict__ in,
                                                  unsigned short* __restrict__ out, int n4){
  int idx = blockIdx.x*256 + threadIdx.x;
  if (idx >= n4) return;
  float4 v = ((const float4*)in)[idx];
  ushort4 o;
  o.x = f2bf(v.x); o.y = f2bf(v.y); o.z = f2bf(v.z); o.w = f2bf(v.w);
  ((ushort4*)out)[idx] = o;
}

// ---------------- w2cat: [4096][2048] = [Whh1 row | Wih1 row] bf16 ----------------
__global__ __launch_bounds__(256) void w2cat_kernel(const float* __restrict__ Whh1,
                                                    const float* __restrict__ Wih1,
                                                    unsigned short* __restrict__ w2){
  int row = blockIdx.x, tid = threadIdx.x;
  const float* a = Whh1 + (size_t)row*1024 + tid*4;
  const float* b = Wih1 + (size_t)row*1024 + tid*4;
  float4 va = *(const float4*)a, vb = *(const float4*)b;
  ushort4 oa, ob;
  oa.x = f2bf(va.x); oa.y = f2bf(va.y); oa.z = f2bf(va.z); oa.w = f2bf(va.w);
  ob.x = f2bf(vb.x); ob.y = f2bf(vb.y); ob.z = f2bf(vb.z); ob.w = f2bf(vb.w);
  *(ushort4*)&w2[(size_t)row*2048 + tid*4]        = oa;
  *(ushort4*)&w2[(size_t)row*2048 + 1024 + tid*4] = ob;
}

// ---------------- bf16 MFMA GEMM (K=8192): xg0 = xl @ Wih0^T + bih0 + bhh0 ----------------
__global__ __launch_bounds__(256) void gemm_bf2(
    const unsigned short* __restrict__ A, const unsigned short* __restrict__ W,
    const float* __restrict__ b1, const float* __restrict__ b2,
    float* __restrict__ Y, int N, int K){
  __shared__ __align__(16) short As[2][64*64];
  __shared__ __align__(16) short Bs[2][128*64];
  int tid = threadIdx.x;
  int id = blockIdx.x;
  int xcd = id & 7, local = id >> 3;
  int nt = xcd*4 + (local & 3), mt = local >> 2;
  int m0 = mt*64, n0 = nt*128;
  int lane = tid & 63;
  int w = tid >> 6, wm = w >> 1, wn = w & 1;
  int lr = lane & 15, ko = lane >> 4;
  int wbase = tid & ~63;

  auto STAGE = [&](int buf, int kc){
    #pragma unroll
    for (int it = 0; it < 2; ++it){
      int chunk = it*256 + tid;
      int r = chunk >> 3, c8 = chunk & 7;
      int cs = (c8 ^ (r & 7)) << 3;
      gload16(&A[(size_t)(m0 + r)*K + kc + cs], &As[buf][(size_t)(it*256 + wbase)*8]);
    }
    #pragma unroll
    for (int it = 0; it < 4; ++it){
      int chunk = it*256 + tid;
      int r = chunk >> 3, c8 = chunk & 7;
      int cs = (c8 ^ (r & 7)) << 3;
      gload16(&W[(size_t)(n0 + r)*K + kc + cs], &Bs[buf][(size_t)(it*256 + wbase)*8]);
    }
  };

  f32x4 zero = {0.f,0.f,0.f,0.f};
  f32x4 acc[2][4] = {{zero,zero,zero,zero},{zero,zero,zero,zero}};

  STAGE(0, 0);
  __syncthreads();
  int nk = K >> 6;
  for (int kt = 0; kt < nk; ++kt){
    int cur = kt & 1;
    if (kt + 1 < nk) STAGE(cur ^ 1, (kt + 1) << 6);
    #pragma unroll
    for (int kk = 0; kk < 2; ++kk){
      int s = kk*4 + ko;
      bf16x8 af[2], bfv[4];
      #pragma unroll
      for (int m = 0; m < 2; ++m){
        int row = wm*32 + m*16 + lr;
        af[m] = *(const bf16x8*)&As[cur][row*64 + ((s ^ (row & 7)) << 3)];
      }
      #pragma unroll
      for (int n = 0; n < 4; ++n){
        int row = wn*64 + n*16 + lr;
        bfv[n] = *(const bf16x8*)&Bs[cur][row*64 + ((s ^ (row & 7)) << 3)];
      }
      #pragma unroll
      for (int m = 0; m < 2; ++m)
        #pragma unroll
        for (int n = 0; n < 4; ++n)
          acc[m][n] = __builtin_amdgcn_mfma_f32_16x16x32_bf16(af[m], bfv[n], acc[m][n], 0, 0, 0);
    }
    __syncthreads();
  }

  #pragma unroll
  for (int m = 0; m < 2; ++m)
    #pragma unroll
    for (int n = 0; n < 4; ++n)
      #pragma unroll
      for (int v = 0; v < 4; ++v){
        int row = m0 + wm*32 + m*16 + ko*4 + v;
        int col = n0 + wn*64 + n*16 + lr;
        Y[(size_t)row*N + col] = acc[m][n][v] + b1[col] + b2[col];
      }
}

// ---------------- fused 2-layer pipelined LSTM step ----------------
// dispatch t (0..64): blocks 0..127 layer1 compute h1[t] (if t<64);
// blocks 128..255 layer2 compute h2[t-1] (if t>=1) with K=2048 = [Whh1 | Wih1].
#define LBLK 128
__global__ __launch_bounds__(512) void lstm_step3(
    const unsigned short* __restrict__ whh0,    // [4096][1024] bf16
    const unsigned short* __restrict__ w2cat,   // [4096][2048] bf16
    const float* __restrict__ xg0,              // [8][64][4096]
    const float* __restrict__ bih1, const float* __restrict__ bhh1,
    unsigned short* __restrict__ h1seq,         // [8][64][1024] bf16
    unsigned short* __restrict__ h2seq,         // [8][64][1024] bf16
    float* __restrict__ c1, float* __restrict__ c2,
    int t){
  __shared__ float red[4][8][64];
  int tid = threadIdx.x;
  int lane = tid & 63, w = tid >> 6;      // 8 waves
  int g = w >> 2, ws = w & 3;
  bool layer2 = (blockIdx.x >= LBLK);
  int lb = layer2 ? (blockIdx.x - LBLK) : blockIdx.x;
  int tau = layer2 ? (t - 1) : t;
  bool active = layer2 ? (t >= 1) : (t < 64);
  if (!active) return;

  int lr = lane & 15, ko = lane >> 4;
  int q = lr >> 2, dl = lr & 3;
  int dim0w = lb*8 + g*4;
  int row = q*H_ + dim0w + dl;

  f32x4 acc = {0.f,0.f,0.f,0.f};
  bf16x8 zero8 = {0,0,0,0,0,0,0,0};
  if (!layer2){
    if (t > 0){
      const unsigned short* wrow = whh0 + (size_t)row*1024 + ws*256;
      const unsigned short* arow = h1seq + ((size_t)(lr & 7)*T_ + (t-1))*H_ + ws*256;
      f32x4 acc2 = {0.f,0.f,0.f,0.f};
      #pragma unroll
      for (int kk = 0; kk < 8; ++kk){
        int kb = kk*32 + ko*8;
        bf16x8 bv = *(const bf16x8*)&wrow[kb];
        bf16x8 av = (lr < 8) ? *(const bf16x8*)&arow[kb] : zero8;
        if (kk & 1) acc2 = __builtin_amdgcn_mfma_f32_16x16x32_bf16(av, bv, acc2, 0, 0, 0);
        else        acc  = __builtin_amdgcn_mfma_f32_16x16x32_bf16(av, bv, acc,  0, 0, 0);
      }
      acc = acc + acc2;
    }
  } else {
    bool azero = (ws < 2) && (tau == 0);
    if (!azero){
      const unsigned short* wrow = w2cat + (size_t)row*2048 + ws*512;
      const unsigned short* arow = (ws < 2)
        ? h2seq + ((size_t)(lr & 7)*T_ + (tau-1))*H_ + ws*512
        : h1seq + ((size_t)(lr & 7)*T_ + tau)*H_ + (ws-2)*512;
      f32x4 acc2 = {0.f,0.f,0.f,0.f};
      #pragma unroll
      for (int kk = 0; kk < 16; ++kk){
        int kb = kk*32 + ko*8;
        bf16x8 bv = *(const bf16x8*)&wrow[kb];
        bf16x8 av = (lr < 8) ? *(const bf16x8*)&arow[kb] : zero8;
        if (kk & 1) acc2 = __builtin_amdgcn_mfma_f32_16x16x32_bf16(av, bv, acc2, 0, 0, 0);
        else        acc  = __builtin_amdgcn_mfma_f32_16x16x32_bf16(av, bv, acc,  0, 0, 0);
      }
      acc = acc + acc2;
    }
  }
  #pragma unroll
  for (int v = 0; v < 4; ++v) red[v][w][lane] = acc[v];
  __syncthreads();

  if (tid < 64){
    int g2 = tid >> 5, b = (tid >> 2) & 7, dl2 = tid & 3;
    int dim = lb*8 + g2*4 + dl2;
    float pre[4];
    #pragma unroll
    for (int qq = 0; qq < 4; ++qq){
      int lsrc = (b >> 2)*16 + qq*4 + dl2, v = b & 3;
      pre[qq] = red[v][g2*4+0][lsrc] + red[v][g2*4+1][lsrc]
              + red[v][g2*4+2][lsrc] + red[v][g2*4+3][lsrc];
    }
    float pi, pf, pg, po;
    if (!layer2){
      size_t xb = ((size_t)b*T_ + t)*4096;
      pi = pre[0] + xg0[xb + 0*H_ + dim];
      pf = pre[1] + xg0[xb + 1*H_ + dim];
      pg = pre[2] + xg0[xb + 2*H_ + dim];
      po = pre[3] + xg0[xb + 3*H_ + dim];
    } else {
      pi = pre[0] + bih1[0*H_ + dim] + bhh1[0*H_ + dim];
      pf = pre[1] + bih1[1*H_ + dim] + bhh1[1*H_ + dim];
      pg = pre[2] + bih1[2*H_ + dim] + bhh1[2*H_ + dim];
      po = pre[3] + bih1[3*H_ + dim] + bhh1[3*H_ + dim];
    }
    float i_ = sigf(pi), f_ = sigf(pf), g_ = tanhf(pg), o_ = sigf(po);
    float* cb = layer2 ? c2 : c1;
    float cp = (tau > 0) ? cb[(size_t)b*H_ + dim] : 0.f;
    float cn = fmaf(f_, cp, i_*g_);
    float hn = o_ * tanhf(cn);
    cb[(size_t)b*H_ + dim] = cn;
    (layer2 ? h2seq : h1seq)[((size_t)b*T_ + tau)*H_ + dim] = f2bf(hn);
  }
}

// ---------------- final head (bf16 h2) ----------------
__global__ __launch_bounds__(128) void final_kernel(
    const unsigned short* __restrict__ h2_seq, const float* __restrict__ Wout,
    const float* __restrict__ bout, float* __restrict__ out){
  int tid = threadIdx.x;
  int b = tid >> 4, nc = tid & 15;
  const unsigned short* hp = h2_seq + ((size_t)b*T_ + (T_ - 1))*H_;
  const float* wp = Wout + nc*H_;
  float acc = bout[nc];
  for (int k = 0; k < 1024; ++k) acc = fmaf(bf2f(hp[k]), wp[k], acc);
  out[tid] = acc;
}

extern "C" void kernel_launch(void* const* d_in, const int* in_sizes, int n_in,
                              void* d_out, int out_size, void* d_ws, size_t ws_size,
                              hipStream_t stream){
  const float* X    = (const float*)d_in[0];
  const float* V    = (const float*)d_in[1];
  const float* Wl   = (const float*)d_in[2];
  const float* bl   = (const float*)d_in[3];
  const float* Wr   = (const float*)d_in[4];
  const float* br   = (const float*)d_in[5];
  const float* att  = (const float*)d_in[6];
  const float* we   = (const float*)d_in[7];
  const float* gb   = (const float*)d_in[8];
  const float* Wfc  = (const float*)d_in[9];
  const float* bfc  = (const float*)d_in[10];
  const float* Wih0 = (const float*)d_in[11];
  const float* Whh0 = (const float*)d_in[12];
  const float* bih0 = (const float*)d_in[13];
  const float* bhh0 = (const float*)d_in[14];
  const float* Wih1 = (const float*)d_in[15];
  const float* Whh1 = (const float*)d_in[16];
  const float* bih1 = (const float*)d_in[17];
  const float* bhh1 = (const float*)d_in[18];
  const float* Wout = (const float*)d_in[19];
  const float* bout = (const float*)d_in[20];

  float* ws   = (float*)d_ws;
  float* attr = ws;                     // 8192
  float* gl0  = attr + 8192;            // 2097152
  float* gr0  = gl0 + 2097152;          // 2097152
  float* xg0  = gr0 + 2097152;          // 2097152
  float* c1   = xg0 + 2097152;          // 8192
  float* c2   = c1 + 8192;              // 8192
  float* bias_comb = c2 + 8192;         // 64
  unsigned short* xl_bf  = (unsigned short*)(bias_comb + 64); // 4194304
  unsigned short* w0_bf  = xl_bf + 4194304;                   // 33554432
  unsigned short* wh0_bf = w0_bf + 33554432;                  // 4194304
  unsigned short* w2_bf  = wh0_bf + 4194304;                  // 8388608
  unsigned short* h1_bf  = w2_bf + 8388608;                   // 524288
  unsigned short* h2_bf  = h1_bf + 524288;                    // 524288
  unsigned short* wlr_bf = h2_bf + 524288;                    // 16384
  unsigned short* wcomb  = wlr_bf + 16384;                    // 2048
  (void)in_sizes; (void)n_in; (void)out_size; (void)ws_size;

  attr_kernel<<<8, 256, 0, stream>>>(V, attr);
  prep_kernel<<<1, 256, 0, stream>>>(Wl, Wr, bl, gb, Wfc, bfc, wcomb, bias_comb, wlr_bf);
  gemm_proj0<<<256, 256, 0, stream>>>(X, wlr_bf, bl, br, gl0, gr0);
  attn_kernel<<<512, 256, 0, stream>>>(gl0, gr0, attr, we, att, gb, Wfc, bfc, xl_bf);
  gemm_rest<<<448, 256, 0, stream>>>(X, wcomb, bias_comb, xl_bf);

  f2b_kernel<<<32768, 256, 0, stream>>>(Wih0, w0_bf, 8388608);
  f2b_kernel<<<4096, 256, 0, stream>>>(Whh0, wh0_bf, 1048576);
  w2cat_kernel<<<4096, 256, 0, stream>>>(Whh1, Wih1, w2_bf);

  gemm_bf2<<<256, 256, 0, stream>>>(xl_bf, w0_bf, bih0, bhh0, xg0, 4096, 8192);

  for (int t = 0; t <= 64; ++t)
    lstm_step3<<<256, 512, 0, stream>>>(wh0_bf, w2_bf, xg0, bih1, bhh1,
                                        h1_bf, h2_bf, c1, c2, t);

  final_kernel<<<1, 128, 0, stream>>>(h2_bf, Wout, bout, (float*)d_out);
}